// Round 8
// baseline (346.745 us; speedup 1.0000x reference)
//
#include <hip/hip_runtime.h>

#define NEG_SLOPE 0.2f

static const int B = 4, N = 50000, R = 100000, E = 1600000;
static const int WI_CAP = 131072;   // wi pairs capacity (expected ~33k)
static const int X2_CAP = 4096;     // x2 edge list capacity (expected ~64)
static const int R2_CAP = 4096;     // distinct t2 rows (expected ~64)
static const int I4PB = 512;        // int4 groups per staged-scan block (2048 edges)

// flagsR bits: 1 = R2 (rows needed for t2), 2 = R1 (rows needed for t1)

// ---------- fusedA: blocks [0,G1) = gemm1 (x->h1), blocks [G1,..) = markA ----------
__global__ void fusedA(const float* __restrict__ x, const float* __restrict__ W1,
                       float* __restrict__ h1,
                       const int4* __restrict__ wi_rows4, const int* __restrict__ wi_cols,
                       const float* __restrict__ wi_val,
                       int* __restrict__ flagsR, int2* __restrict__ x2list,
                       int* __restrict__ x2tail, int* __restrict__ r2list,
                       int* __restrict__ r2tail, int e4, int G1) {
    if ((int)blockIdx.x < G1) {
        __shared__ float sW[32 * 32];
        for (int i = threadIdx.x; i < 1024; i += blockDim.x) sW[i] = W1[i];
        __syncthreads();
        int id = blockIdx.x * blockDim.x + threadIdx.x;
        if (id >= N * B) return;
        int n = id >> 2, b = id & 3;
        const float* xr = x + ((size_t)b * N + n) * 32;
        float acc[32];
#pragma unroll
        for (int c = 0; c < 32; ++c) acc[c] = 0.f;
#pragma unroll
        for (int k = 0; k < 32; ++k) {
            float xv = xr[k];
#pragma unroll
            for (int c = 0; c < 32; ++c) acc[c] += xv * sW[k * 32 + c];
        }
        float* o = h1 + ((size_t)n * B + b) * 32;
#pragma unroll
        for (int c = 0; c < 32; ++c) o[c] = acc[c];
    } else {
        int blk = blockIdx.x - G1;
        int base = blk * (blockDim.x * 4) + threadIdx.x;
#pragma unroll
        for (int k = 0; k < 4; ++k) {
            int i = base + k * blockDim.x;
            if (i >= e4) continue;
            int4 r = wi_rows4[i];
            int rr[4] = {r.x, r.y, r.z, r.w};
#pragma unroll
            for (int j = 0; j < 4; ++j) {
                if (rr[j] >= N - 2) {
                    int ed = i * 4 + j;
                    int col = wi_cols[ed];
                    int old = atomicOr(&flagsR[col], 1);
                    if (!(old & 1)) {
                        int p = atomicAdd(r2tail, 1);
                        if (p < R2_CAP) r2list[p] = col;
                    }
                    int pos = atomicAdd(x2tail, 1);   // ~64 total: negligible
                    if (pos < X2_CAP)
                        x2list[pos] = make_int2(col * 2 + (rr[j] - (N - 2)),
                                                __float_as_int(wi_val[ed]));
                }
            }
        }
    }
}

// ---------- markB: w edges with flagged row -> flagN1[col] + staged n1list ----------
__global__ void markB(const int4* __restrict__ w_rows4, const int* __restrict__ w_cols,
                      const int* __restrict__ flagsR, int* __restrict__ flagN1,
                      int* __restrict__ n1list, int* __restrict__ n1tail, int e4) {
    __shared__ int lcount, gbase;
    __shared__ int sbuf[2048];
    if (threadIdx.x == 0) lcount = 0;
    __syncthreads();
    int lane = threadIdx.x & 63;
#pragma unroll
    for (int k = 0; k < 2; ++k) {
        int i = blockIdx.x * I4PB + k * 256 + threadIdx.x;
        int4 r = make_int4(-1, -1, -1, -1);
        if (i < e4) r = w_rows4[i];
        int rr[4] = {r.x, r.y, r.z, r.w};
#pragma unroll
        for (int j = 0; j < 4; ++j) {
            bool isnew = false;
            int c = 0;
            if (rr[j] >= 0 && flagsR[rr[j]] != 0) {
                c = w_cols[i * 4 + j];
                int old = atomicOr(&flagN1[c], 1);
                isnew = (old == 0);
            }
            unsigned long long m = __ballot(isnew);
            if (m) {
                int leader = __ffsll(m) - 1;
                int b0 = 0;
                if (lane == leader) b0 = atomicAdd(&lcount, __popcll(m));
                b0 = __shfl(b0, leader);
                if (isnew) sbuf[b0 + __popcll(m & ((1ull << lane) - 1))] = c;
            }
        }
    }
    __syncthreads();
    if (threadIdx.x == 0) gbase = atomicAdd(n1tail, lcount);
    __syncthreads();
    for (int t = threadIdx.x; t < lcount; t += blockDim.x) n1list[gbase + t] = sbuf[t];
}

// ---- markC_wi: wi edges with flagN1 row -> flagsR bit1 + r1list, wi hist, staging --
__global__ void markC_wi(const int4* __restrict__ wi_rows4, const int* __restrict__ wi_cols,
                         const float* __restrict__ wi_val, const float* __restrict__ diag1,
                         const int* __restrict__ flagN1,
                         int* __restrict__ flagsR, int* __restrict__ wi_cnt,
                         int2* __restrict__ wi_rc, float* __restrict__ wi_cf,
                         int* __restrict__ witail,
                         int* __restrict__ r1list, int* __restrict__ r1tail, int e4) {
    __shared__ int lcount, gbase, lcount2, gbase2;
    __shared__ int2 srec[2048];
    __shared__ float scf[2048];
    __shared__ int r1buf[2048];
    if (threadIdx.x == 0) { lcount = 0; lcount2 = 0; }
    __syncthreads();
    int lane = threadIdx.x & 63;
#pragma unroll
    for (int k = 0; k < 2; ++k) {
        int i = blockIdx.x * I4PB + k * 256 + threadIdx.x;
        int4 r = make_int4(-1, -1, -1, -1);
        if (i < e4) r = wi_rows4[i];
        int rr[4] = {r.x, r.y, r.z, r.w};
#pragma unroll
        for (int j = 0; j < 4; ++j) {
            bool pass = (rr[j] >= 0) && (flagN1[rr[j]] != 0);
            bool isnew = false;
            int col = 0; float cf = 0.f;
            if (pass) {
                int ed = i * 4 + j;
                col = wi_cols[ed];
                cf = wi_val[ed] * diag1[col];
                atomicAdd(&wi_cnt[rr[j]], 1);     // distributed: fine
                int old = atomicOr(&flagsR[col], 2);
                isnew = !(old & 2);
            }
            unsigned long long m = __ballot(pass);
            if (m) {
                int leader = __ffsll(m) - 1;
                int b0 = 0;
                if (lane == leader) b0 = atomicAdd(&lcount, __popcll(m));
                b0 = __shfl(b0, leader);
                if (pass) {
                    int pos = b0 + __popcll(m & ((1ull << lane) - 1));
                    srec[pos] = make_int2(rr[j], col);
                    scf[pos] = cf;
                }
            }
            unsigned long long m2 = __ballot(isnew);
            if (m2) {
                int leader = __ffsll(m2) - 1;
                int b0 = 0;
                if (lane == leader) b0 = atomicAdd(&lcount2, __popcll(m2));
                b0 = __shfl(b0, leader);
                if (isnew) r1buf[b0 + __popcll(m2 & ((1ull << lane) - 1))] = col;
            }
        }
    }
    __syncthreads();
    if (threadIdx.x == 0) {
        gbase = atomicAdd(witail, lcount);
        gbase2 = atomicAdd(r1tail, lcount2);
    }
    __syncthreads();
    for (int t = threadIdx.x; t < lcount; t += blockDim.x) {
        int g = gbase + t;
        if (g < WI_CAP) { wi_rc[g] = srec[t]; wi_cf[g] = scf[t]; }
    }
    for (int t = threadIdx.x; t < lcount2; t += blockDim.x) r1list[gbase2 + t] = r1buf[t];
}

// ---------- whist: w edges with flagsR row -> w hist + staged (row,col,val) ------
__global__ void whist(const int4* __restrict__ w_rows4, const int* __restrict__ w_cols,
                      const float* __restrict__ w_val, const int* __restrict__ flagsR,
                      int* __restrict__ w_cnt, int2* __restrict__ w_srec,
                      float* __restrict__ w_sval, int* __restrict__ wtail, int e4) {
    __shared__ int lcount, gbase;
    __shared__ int2 srec[2048];
    __shared__ float sval[2048];
    if (threadIdx.x == 0) lcount = 0;
    __syncthreads();
    int lane = threadIdx.x & 63;
#pragma unroll
    for (int k = 0; k < 2; ++k) {
        int i = blockIdx.x * I4PB + k * 256 + threadIdx.x;
        int4 r = make_int4(-1, -1, -1, -1);
        if (i < e4) r = w_rows4[i];
        int rr[4] = {r.x, r.y, r.z, r.w};
#pragma unroll
        for (int j = 0; j < 4; ++j) {
            bool pass = (rr[j] >= 0) && (flagsR[rr[j]] != 0);
            int col = 0; float v = 0.f;
            if (pass) {
                int ed = i * 4 + j;
                col = w_cols[ed];
                v = w_val[ed];
                atomicAdd(&w_cnt[rr[j]], 1);
            }
            unsigned long long m = __ballot(pass);
            if (m) {
                int leader = __ffsll(m) - 1;
                int b0 = 0;
                if (lane == leader) b0 = atomicAdd(&lcount, __popcll(m));
                b0 = __shfl(b0, leader);
                if (pass) {
                    int pos = b0 + __popcll(m & ((1ull << lane) - 1));
                    srec[pos] = make_int2(rr[j], col);
                    sval[pos] = v;
                }
            }
        }
    }
    __syncthreads();
    if (threadIdx.x == 0) gbase = atomicAdd(wtail, lcount);
    __syncthreads();
    for (int t = threadIdx.x; t < lcount; t += blockDim.x) {
        w_srec[gbase + t] = srec[t];
        w_sval[gbase + t] = sval[t];
    }
}

// ------- segment base assignment for both CSRs in one dispatch (order-free) -----
__global__ void assign_offsets2(const int* __restrict__ cntA, int nA, int* __restrict__ offA,
                                const int* __restrict__ cntB, int nB, int* __restrict__ offB,
                                int* __restrict__ gcur) {
    int nBlocksA = (nA + 255) / 256;
    bool isA = (int)blockIdx.x < nBlocksA;
    const int* cnt = isA ? cntA : cntB;
    int* off = isA ? offA : offB;
    int n = isA ? nA : nB;
    int* gc = gcur + (isA ? 0 : 1);
    int blk = isA ? blockIdx.x : (blockIdx.x - nBlocksA);
    int i = blk * 256 + threadIdx.x;
    int tid = threadIdx.x;
    int v = (i < n) ? cnt[i] : 0;
    __shared__ int s[256];
    s[tid] = v;
    __syncthreads();
#pragma unroll
    for (int d = 1; d < 256; d <<= 1) {
        int t = (tid >= d) ? s[tid - d] : 0;
        __syncthreads();
        s[tid] += t;
        __syncthreads();
    }
    int incl = s[tid];
    __shared__ int base;
    if (tid == 255) base = atomicAdd(gc, incl);
    __syncthreads();
    if (i < n) off[i] = base + incl - v;
}

// ---------- place both CSRs from staged records (linear reads, grid-stride) ------
__global__ void place_fused(const int2* __restrict__ w_srec, const float* __restrict__ w_sval,
                            const int* __restrict__ wtail,
                            const int* __restrict__ w_off, int* __restrict__ w_cur,
                            const int2* __restrict__ wi_rc, const float* __restrict__ wi_cf,
                            const int* __restrict__ witail,
                            const int* __restrict__ wi_off, int* __restrict__ wi_cur,
                            int2* __restrict__ w_pairs, int2* __restrict__ wi_pairs) {
    int wt = *wtail;
    int wit = *witail; if (wit > WI_CAP) wit = WI_CAP;
    int total = wt + wit;
    int stride = gridDim.x * blockDim.x;
    for (int i = blockIdx.x * blockDim.x + threadIdx.x; i < total; i += stride) {
        if (i < wt) {
            int2 rc = w_srec[i];
            int pos = w_off[rc.x] + atomicAdd(&w_cur[rc.x], 1);
            w_pairs[pos] = make_int2(rc.y, __float_as_int(w_sval[i]));
        } else {
            int j = i - wt;
            int2 rc = wi_rc[j];
            int pos = wi_off[rc.x] + atomicAdd(&wi_cur[rc.x], 1);
            wi_pairs[pos] = make_int2(rc.y, __float_as_int(wi_cf[j]));
        }
    }
}

// ---- list-driven CSR gather, [node][B][C] layout, float4/thread, grid-stride ----
template<int C>
__global__ void gather_list(const float* __restrict__ src, float* __restrict__ dst,
                            const int* __restrict__ off, const int* __restrict__ len,
                            const int2* __restrict__ pairs, const int* __restrict__ rowlist,
                            const int* __restrict__ rowcount) {
    constexpr int C4 = C / 4;
    constexpr int TPR = C4 * B;
    constexpr int STRIDE = B * C4;        // float4 stride per source node block
    int total = (*rowcount) * TPR;
    int gstride = gridDim.x * blockDim.x;
    for (int idx = blockIdx.x * blockDim.x + threadIdx.x; idx < total; idx += gstride) {
        int row = rowlist[idx / TPR];
        int rem = idx & (TPR - 1);
        int c4 = rem & (C4 - 1);
        int b = rem / C4;
        int s = off[row];
        int L = len[row];
        const float4* sb = (const float4*)src + b * C4 + c4;
        float4 acc = make_float4(0.f, 0.f, 0.f, 0.f);
        int i = s;
        int e4i = s + (L & ~3);
        for (; i < e4i; i += 4) {
            int2 p0 = pairs[i + 0];
            int2 p1 = pairs[i + 1];
            int2 p2 = pairs[i + 2];
            int2 p3 = pairs[i + 3];
            float4 s0 = sb[(size_t)p0.x * STRIDE];
            float4 s1 = sb[(size_t)p1.x * STRIDE];
            float4 s2 = sb[(size_t)p2.x * STRIDE];
            float4 s3 = sb[(size_t)p3.x * STRIDE];
            float v0 = __int_as_float(p0.y), v1 = __int_as_float(p1.y);
            float v2 = __int_as_float(p2.y), v3 = __int_as_float(p3.y);
            acc.x += v0 * s0.x + v1 * s1.x + v2 * s2.x + v3 * s3.x;
            acc.y += v0 * s0.y + v1 * s1.y + v2 * s2.y + v3 * s3.y;
            acc.z += v0 * s0.z + v1 * s1.z + v2 * s2.z + v3 * s3.z;
            acc.w += v0 * s0.w + v1 * s1.w + v2 * s2.w + v3 * s3.w;
        }
        for (; i < s + L; ++i) {
            int2 p = pairs[i];
            float4 sv = sb[(size_t)p.x * STRIDE];
            float v = __int_as_float(p.y);
            acc.x += v * sv.x; acc.y += v * sv.y; acc.z += v * sv.z; acc.w += v * sv.w;
        }
        ((float4*)dst)[(size_t)row * STRIDE + b * C4 + c4] = acc;
    }
}

// ---------- grid barrier for the tail kernel (small co-resident grid) ----------
__device__ inline void grid_sync(int* bar, int nb, int target) {
    __syncthreads();
    if (threadIdx.x == 0) {
        __threadfence();
        atomicAdd(bar, 1);
        while (atomicAdd(bar, 0) < nb * target) __builtin_amdgcn_s_sleep(2);
        __threadfence();
    }
    __syncthreads();
}

// ---- tail: gemm2 (n1 rows) -> barrier -> t2 gather (r2 rows) -> barrier -> heads --
__global__ void tail_kernel(const float* __restrict__ x1, const float* __restrict__ W2,
                            float* __restrict__ h2,
                            const int* __restrict__ n1list, const int* __restrict__ n1tail,
                            const int* __restrict__ w_off, const int* __restrict__ w_cnt,
                            const int2* __restrict__ w_pairs,
                            const int* __restrict__ r2list, const int* __restrict__ r2tail,
                            float* __restrict__ t2,
                            const int2* __restrict__ x2list, const int* __restrict__ x2tail,
                            const float* __restrict__ diag2,
                            const float* __restrict__ rw1, const float* __restrict__ rb1,
                            const float* __restrict__ rw2, const float* __restrict__ rb2,
                            float* __restrict__ out, int* __restrict__ bar) {
    __shared__ float sW[32 * 16];
    for (int i = threadIdx.x; i < 512; i += blockDim.x) sW[i] = W2[i];
    __syncthreads();
    int nb = gridDim.x;
    int gstride = nb * blockDim.x;

    // phase A: gemm2 over n1count*B ids (lrelu on x1 input)
    int n1c = *n1tail;
    for (int id = blockIdx.x * blockDim.x + threadIdx.x; id < n1c * B; id += gstride) {
        int n = n1list[id >> 2];
        int b = id & 3;
        const float* xr = x1 + ((size_t)n * B + b) * 32;
        float acc[16];
#pragma unroll
        for (int c = 0; c < 16; ++c) acc[c] = 0.f;
#pragma unroll
        for (int k = 0; k < 32; ++k) {
            float xv = xr[k];
            xv = xv > 0.f ? xv : NEG_SLOPE * xv;
#pragma unroll
            for (int c = 0; c < 16; ++c) acc[c] += xv * sW[k * 16 + c];
        }
        float* o = h2 + ((size_t)n * B + b) * 16;
#pragma unroll
        for (int c = 0; c < 16; ++c) o[c] = acc[c];
    }
    grid_sync(bar, nb, 1);

    // phase B: t2 gather over r2 rows, 16 float4-lanes per row
    int r2c = *r2tail; if (r2c > R2_CAP) r2c = R2_CAP;
    for (int idx = blockIdx.x * blockDim.x + threadIdx.x; idx < r2c * 16; idx += gstride) {
        int row = r2list[idx >> 4];
        int rem = idx & 15;
        int c4 = rem & 3;
        int b = rem >> 2;
        int s = w_off[row];
        int L = w_cnt[row];
        const float4* sb = (const float4*)h2 + b * 4 + c4;
        float4 acc = make_float4(0.f, 0.f, 0.f, 0.f);
        for (int i = s; i < s + L; ++i) {
            int2 p = w_pairs[i];
            float4 sv = sb[(size_t)p.x * 16];
            float v = __int_as_float(p.y);
            acc.x += v * sv.x; acc.y += v * sv.y; acc.z += v * sv.z; acc.w += v * sv.w;
        }
        ((float4*)t2)[(size_t)row * 16 + b * 4 + c4] = acc;
    }
    grid_sync(bar, nb, 2);

    // phase C: x2 accumulation (edge-parallel) + heads, block 0
    if (blockIdx.x == 0) {
        int cnt = *x2tail; if (cnt > X2_CAP) cnt = X2_CAP;
        int g = threadIdx.x >> 6, l = threadIdx.x & 63;
        int b = l >> 4, c = l & 15;
        float a0 = 0.f, a1 = 0.f;
        for (int i = g; i < cnt; i += 4) {
            int2 rec = x2list[i];
            int col = rec.x >> 1;
            float coef = __int_as_float(rec.y) * diag2[col];
            float v = t2[((size_t)col * B + b) * 16 + c] * coef;
            if (rec.x & 1) a1 += v; else a0 += v;
        }
        __shared__ float red0[4][64], red1[4][64], xs[2][64];
        red0[g][l] = a0; red1[g][l] = a1;
        __syncthreads();
        if (g == 0) {
            xs[0][l] = red0[0][l] + red0[1][l] + red0[2][l] + red0[3][l];
            xs[1][l] = red1[0][l] + red1[1][l] + red1[2][l] + red1[3][l];
        }
        __syncthreads();
        if (threadIdx.x < 8) {
            int bb = threadIdx.x >> 1, which = threadIdx.x & 1;
            const float* w = which ? rw2 : rw1;
            float acc = which ? rb2[0] : rb1[0];
            for (int k = 0; k < 16; ++k) {
                float xv = xs[which][bb * 16 + k];
                xv = xv > 0.f ? xv : NEG_SLOPE * xv;
                acc += xv * w[k];
            }
            out[bb * 2 + which] = acc;
        }
    }
}

extern "C" void kernel_launch(void* const* d_in, const int* in_sizes, int n_in,
                              void* d_out, int out_size, void* d_ws, size_t ws_size,
                              hipStream_t stream) {
    const int*   w_rows  = (const int*)d_in[0];
    const int*   w_cols  = ((const int*)d_in[0]) + E;
    const float* w_val   = (const float*)d_in[1];
    const int*   wi_rows = (const int*)d_in[2];
    const int*   wi_cols = ((const int*)d_in[2]) + E;
    const float* wi_val  = (const float*)d_in[3];
    const float* x       = (const float*)d_in[4];
    const float* W1      = (const float*)d_in[5];
    const float* diag1   = (const float*)d_in[6];
    const float* W2      = (const float*)d_in[7];
    const float* diag2   = (const float*)d_in[8];
    const float* rw1     = (const float*)d_in[9];
    const float* rb1     = (const float*)d_in[10];
    const float* rw2     = (const float*)d_in[11];
    const float* rb2     = (const float*)d_in[12];
    float* out = (float*)d_out;

    // ---------------- workspace layout ----------------
    float* h1   = (float*)d_ws;                 // [N][B][32]; later aliased as x1
    float* treg = h1 + (size_t)B * N * 32;      // 12.8M floats: staging early; t1; h2+t2 later
    int* ip = (int*)(treg + (size_t)B * R * 32);
    // zeroed block:
    int* w_cnt  = ip; ip += R;
    int* w_off  = ip; ip += R;
    int* w_cur  = ip; ip += R;
    int* wi_cnt = ip; ip += N;
    int* wi_off = ip; ip += N;
    int* wi_cur = ip; ip += N;
    int* flagsR = ip; ip += R;
    int* flagN1 = ip; ip += N;
    int* gcur   = ip; ip += 2;
    int* tails  = ip; ip += 4;   // [0]=wtail [1]=witail [2]=x2tail
    int* misc   = ip; ip += 4;   // [0]=r1tail [1]=n1tail [2]=r2tail [3]=bar
    size_t zero_words = (size_t)(ip - w_cnt);
    // un-zeroed:
    int2* w_pairs  = (int2*)ip; ip += 2 * E;
    int2* wi_pairs = (int2*)ip; ip += 2 * WI_CAP;
    int2* x2list   = (int2*)ip; ip += 2 * X2_CAP;
    int*  r2list   = ip; ip += R2_CAP;
    int*  n1list   = ip; ip += N;
    int*  r1list   = ip; ip += R;
    // staging buffers aliased inside treg (dead before t1 is written):
    int2*  w_srec = (int2*)treg;                                   // up to E
    float* w_sval = treg + (size_t)2 * E;                          // up to E
    int2*  wi_rc  = (int2*)(treg + (size_t)3 * E);                 // WI_CAP
    float* wi_cf  = treg + (size_t)3 * E + (size_t)2 * WI_CAP;     // WI_CAP

    float* x1 = h1;                          // alias
    float* h2 = treg;                        // [N][B][16]
    float* t2 = treg + (size_t)B * N * 16;   // [R][B][16]

    const int blk = 256;
    const int e4 = E / 4;
    const int G1 = (N * B + blk - 1) / blk;            // gemm1 blocks
    const int G2 = (e4 + blk * 4 - 1) / (blk * 4);     // markA blocks
    const int stageGrid = (e4 + I4PB - 1) / I4PB;

    (void)hipMemsetAsync(w_cnt, 0, zero_words * sizeof(int), stream);

    // ---- gemm1 + markA fused (independent work, one dispatch) ----
    fusedA<<<G1 + G2, blk, 0, stream>>>(x, W1, h1, (const int4*)wi_rows, wi_cols, wi_val,
                                        flagsR, x2list, tails + 2, r2list, misc + 2, e4, G1);
    markB<<<stageGrid, blk, 0, stream>>>((const int4*)w_rows, w_cols, flagsR, flagN1,
                                         n1list, misc + 1, e4);
    markC_wi<<<stageGrid, blk, 0, stream>>>((const int4*)wi_rows, wi_cols, wi_val, diag1,
                                            flagN1, flagsR, wi_cnt, wi_rc, wi_cf,
                                            tails + 1, r1list, misc + 0, e4);
    whist<<<stageGrid, blk, 0, stream>>>((const int4*)w_rows, w_cols, w_val, flagsR,
                                         w_cnt, w_srec, w_sval, tails + 0, e4);
    {
        int nBlocks = (R + 255) / 256 + (N + 255) / 256;
        assign_offsets2<<<nBlocks, 256, 0, stream>>>(w_cnt, R, w_off, wi_cnt, N, wi_off, gcur);
    }
    place_fused<<<512, blk, 0, stream>>>(w_srec, w_sval, tails + 0, w_off, w_cur,
                                         wi_rc, wi_cf, tails + 1, wi_off, wi_cur,
                                         w_pairs, wi_pairs);

    // ---- layer 1 gathers (list-driven, grid-stride) ----
    gather_list<32><<<4096, blk, 0, stream>>>(h1, treg, w_off, w_cnt, w_pairs,
                                              r1list, misc + 0);       // t1
    gather_list<32><<<256, blk, 0, stream>>>(treg, x1, wi_off, wi_cnt, wi_pairs,
                                             n1list, misc + 1);        // x1

    // ---- tail: gemm2 + t2 gather + x2/heads in one kernel (grid barriers) ----
    tail_kernel<<<64, blk, 0, stream>>>(x1, W2, h2, n1list, misc + 1,
                                        w_off, w_cnt, w_pairs, r2list, misc + 2,
                                        t2, x2list, tails + 2, diag2,
                                        rw1, rb1, rw2, rb2, out, misc + 3);
}

// Round 9
// 342.253 us; speedup vs baseline: 1.0131x; 1.0131x over previous
//
#include <hip/hip_runtime.h>

#define NEG_SLOPE 0.2f

static const int B = 4, N = 50000, R = 100000, E = 1600000;
static const int WI_CAP = 131072;   // wi pairs capacity (expected ~33k)
static const int X2_CAP = 4096;     // x2 edge list capacity (expected ~64)
static const int R2_CAP = 4096;     // distinct t2 rows (expected ~64)
static const int I4PB = 512;        // int4 groups per staged-scan block (2048 edges)

// flagsR bits: 1 = R2 (rows needed for t2), 2 = R1 (rows needed for t1)

// ---------- fusedA: blocks [0,G1) = gemm1 (x->h1), blocks [G1,..) = markA ----------
__global__ void fusedA(const float* __restrict__ x, const float* __restrict__ W1,
                       float* __restrict__ h1,
                       const int4* __restrict__ wi_rows4, const int* __restrict__ wi_cols,
                       const float* __restrict__ wi_val,
                       int* __restrict__ flagsR, int2* __restrict__ x2list,
                       int* __restrict__ x2tail, int* __restrict__ r2list,
                       int* __restrict__ r2tail, int e4, int G1) {
    if ((int)blockIdx.x < G1) {
        __shared__ float sW[32 * 32];
        for (int i = threadIdx.x; i < 1024; i += blockDim.x) sW[i] = W1[i];
        __syncthreads();
        int id = blockIdx.x * blockDim.x + threadIdx.x;
        if (id >= N * B) return;
        int n = id >> 2, b = id & 3;
        const float* xr = x + ((size_t)b * N + n) * 32;
        float acc[32];
#pragma unroll
        for (int c = 0; c < 32; ++c) acc[c] = 0.f;
#pragma unroll
        for (int k = 0; k < 32; ++k) {
            float xv = xr[k];
#pragma unroll
            for (int c = 0; c < 32; ++c) acc[c] += xv * sW[k * 32 + c];
        }
        float* o = h1 + ((size_t)n * B + b) * 32;
#pragma unroll
        for (int c = 0; c < 32; ++c) o[c] = acc[c];
    } else {
        int blk = blockIdx.x - G1;
        int base = blk * (blockDim.x * 4) + threadIdx.x;
#pragma unroll
        for (int k = 0; k < 4; ++k) {
            int i = base + k * blockDim.x;
            if (i >= e4) continue;
            int4 r = wi_rows4[i];
            int rr[4] = {r.x, r.y, r.z, r.w};
#pragma unroll
            for (int j = 0; j < 4; ++j) {
                if (rr[j] >= N - 2) {
                    int ed = i * 4 + j;
                    int col = wi_cols[ed];
                    int old = atomicOr(&flagsR[col], 1);
                    if (!(old & 1)) {
                        int p = atomicAdd(r2tail, 1);
                        if (p < R2_CAP) r2list[p] = col;
                    }
                    int pos = atomicAdd(x2tail, 1);   // ~64 total: negligible
                    if (pos < X2_CAP)
                        x2list[pos] = make_int2(col * 2 + (rr[j] - (N - 2)),
                                                __float_as_int(wi_val[ed]));
                }
            }
        }
    }
}

// ---------- markB: w edges with flagged row -> flagN1[col] + staged n1list ----------
__global__ void markB(const int4* __restrict__ w_rows4, const int* __restrict__ w_cols,
                      const int* __restrict__ flagsR, int* __restrict__ flagN1,
                      int* __restrict__ n1list, int* __restrict__ n1tail, int e4) {
    __shared__ int lcount, gbase;
    __shared__ int sbuf[2048];
    if (threadIdx.x == 0) lcount = 0;
    __syncthreads();
    int lane = threadIdx.x & 63;
#pragma unroll
    for (int k = 0; k < 2; ++k) {
        int i = blockIdx.x * I4PB + k * 256 + threadIdx.x;
        int4 r = make_int4(-1, -1, -1, -1);
        if (i < e4) r = w_rows4[i];
        int rr[4] = {r.x, r.y, r.z, r.w};
#pragma unroll
        for (int j = 0; j < 4; ++j) {
            bool isnew = false;
            int c = 0;
            if (rr[j] >= 0 && flagsR[rr[j]] != 0) {
                c = w_cols[i * 4 + j];
                int old = atomicOr(&flagN1[c], 1);
                isnew = (old == 0);
            }
            unsigned long long m = __ballot(isnew);
            if (m) {
                int leader = __ffsll(m) - 1;
                int b0 = 0;
                if (lane == leader) b0 = atomicAdd(&lcount, __popcll(m));
                b0 = __shfl(b0, leader);
                if (isnew) sbuf[b0 + __popcll(m & ((1ull << lane) - 1))] = c;
            }
        }
    }
    __syncthreads();
    if (threadIdx.x == 0) gbase = atomicAdd(n1tail, lcount);
    __syncthreads();
    for (int t = threadIdx.x; t < lcount; t += blockDim.x) n1list[gbase + t] = sbuf[t];
}

// ---- markC_wi: wi edges with flagN1 row -> flagsR bit1 + r1list, wi hist, staging --
__global__ void markC_wi(const int4* __restrict__ wi_rows4, const int* __restrict__ wi_cols,
                         const float* __restrict__ wi_val, const float* __restrict__ diag1,
                         const int* __restrict__ flagN1,
                         int* __restrict__ flagsR, int* __restrict__ wi_cnt,
                         int2* __restrict__ wi_rc, float* __restrict__ wi_cf,
                         int* __restrict__ witail,
                         int* __restrict__ r1list, int* __restrict__ r1tail, int e4) {
    __shared__ int lcount, gbase, lcount2, gbase2;
    __shared__ int2 srec[2048];
    __shared__ float scf[2048];
    __shared__ int r1buf[2048];
    if (threadIdx.x == 0) { lcount = 0; lcount2 = 0; }
    __syncthreads();
    int lane = threadIdx.x & 63;
#pragma unroll
    for (int k = 0; k < 2; ++k) {
        int i = blockIdx.x * I4PB + k * 256 + threadIdx.x;
        int4 r = make_int4(-1, -1, -1, -1);
        if (i < e4) r = wi_rows4[i];
        int rr[4] = {r.x, r.y, r.z, r.w};
#pragma unroll
        for (int j = 0; j < 4; ++j) {
            bool pass = (rr[j] >= 0) && (flagN1[rr[j]] != 0);
            bool isnew = false;
            int col = 0; float cf = 0.f;
            if (pass) {
                int ed = i * 4 + j;
                col = wi_cols[ed];
                cf = wi_val[ed] * diag1[col];
                atomicAdd(&wi_cnt[rr[j]], 1);     // distributed: fine
                int old = atomicOr(&flagsR[col], 2);
                isnew = !(old & 2);
            }
            unsigned long long m = __ballot(pass);
            if (m) {
                int leader = __ffsll(m) - 1;
                int b0 = 0;
                if (lane == leader) b0 = atomicAdd(&lcount, __popcll(m));
                b0 = __shfl(b0, leader);
                if (pass) {
                    int pos = b0 + __popcll(m & ((1ull << lane) - 1));
                    srec[pos] = make_int2(rr[j], col);
                    scf[pos] = cf;
                }
            }
            unsigned long long m2 = __ballot(isnew);
            if (m2) {
                int leader = __ffsll(m2) - 1;
                int b0 = 0;
                if (lane == leader) b0 = atomicAdd(&lcount2, __popcll(m2));
                b0 = __shfl(b0, leader);
                if (isnew) r1buf[b0 + __popcll(m2 & ((1ull << lane) - 1))] = col;
            }
        }
    }
    __syncthreads();
    if (threadIdx.x == 0) {
        gbase = atomicAdd(witail, lcount);
        gbase2 = atomicAdd(r1tail, lcount2);
    }
    __syncthreads();
    for (int t = threadIdx.x; t < lcount; t += blockDim.x) {
        int g = gbase + t;
        if (g < WI_CAP) { wi_rc[g] = srec[t]; wi_cf[g] = scf[t]; }
    }
    for (int t = threadIdx.x; t < lcount2; t += blockDim.x) r1list[gbase2 + t] = r1buf[t];
}

// ---------- whist: w edges with flagsR row -> w hist + staged (row,col,val) ------
__global__ void whist(const int4* __restrict__ w_rows4, const int* __restrict__ w_cols,
                      const float* __restrict__ w_val, const int* __restrict__ flagsR,
                      int* __restrict__ w_cnt, int2* __restrict__ w_srec,
                      float* __restrict__ w_sval, int* __restrict__ wtail, int e4) {
    __shared__ int lcount, gbase;
    __shared__ int2 srec[2048];
    __shared__ float sval[2048];
    if (threadIdx.x == 0) lcount = 0;
    __syncthreads();
    int lane = threadIdx.x & 63;
#pragma unroll
    for (int k = 0; k < 2; ++k) {
        int i = blockIdx.x * I4PB + k * 256 + threadIdx.x;
        int4 r = make_int4(-1, -1, -1, -1);
        if (i < e4) r = w_rows4[i];
        int rr[4] = {r.x, r.y, r.z, r.w};
#pragma unroll
        for (int j = 0; j < 4; ++j) {
            bool pass = (rr[j] >= 0) && (flagsR[rr[j]] != 0);
            int col = 0; float v = 0.f;
            if (pass) {
                int ed = i * 4 + j;
                col = w_cols[ed];
                v = w_val[ed];
                atomicAdd(&w_cnt[rr[j]], 1);
            }
            unsigned long long m = __ballot(pass);
            if (m) {
                int leader = __ffsll(m) - 1;
                int b0 = 0;
                if (lane == leader) b0 = atomicAdd(&lcount, __popcll(m));
                b0 = __shfl(b0, leader);
                if (pass) {
                    int pos = b0 + __popcll(m & ((1ull << lane) - 1));
                    srec[pos] = make_int2(rr[j], col);
                    sval[pos] = v;
                }
            }
        }
    }
    __syncthreads();
    if (threadIdx.x == 0) gbase = atomicAdd(wtail, lcount);
    __syncthreads();
    for (int t = threadIdx.x; t < lcount; t += blockDim.x) {
        w_srec[gbase + t] = srec[t];
        w_sval[gbase + t] = sval[t];
    }
}

// ------- segment base assignment for both CSRs in one dispatch (order-free) -----
__global__ void assign_offsets2(const int* __restrict__ cntA, int nA, int* __restrict__ offA,
                                const int* __restrict__ cntB, int nB, int* __restrict__ offB,
                                int* __restrict__ gcur) {
    int nBlocksA = (nA + 255) / 256;
    bool isA = (int)blockIdx.x < nBlocksA;
    const int* cnt = isA ? cntA : cntB;
    int* off = isA ? offA : offB;
    int n = isA ? nA : nB;
    int* gc = gcur + (isA ? 0 : 1);
    int blk = isA ? blockIdx.x : (blockIdx.x - nBlocksA);
    int i = blk * 256 + threadIdx.x;
    int tid = threadIdx.x;
    int v = (i < n) ? cnt[i] : 0;
    __shared__ int s[256];
    s[tid] = v;
    __syncthreads();
#pragma unroll
    for (int d = 1; d < 256; d <<= 1) {
        int t = (tid >= d) ? s[tid - d] : 0;
        __syncthreads();
        s[tid] += t;
        __syncthreads();
    }
    int incl = s[tid];
    __shared__ int base;
    if (tid == 255) base = atomicAdd(gc, incl);
    __syncthreads();
    if (i < n) off[i] = base + incl - v;
}

// ---------- place both CSRs from staged records (linear reads, grid-stride) ------
__global__ void place_fused(const int2* __restrict__ w_srec, const float* __restrict__ w_sval,
                            const int* __restrict__ wtail,
                            const int* __restrict__ w_off, int* __restrict__ w_cur,
                            const int2* __restrict__ wi_rc, const float* __restrict__ wi_cf,
                            const int* __restrict__ witail,
                            const int* __restrict__ wi_off, int* __restrict__ wi_cur,
                            int2* __restrict__ w_pairs, int2* __restrict__ wi_pairs) {
    int wt = *wtail;
    int wit = *witail; if (wit > WI_CAP) wit = WI_CAP;
    int total = wt + wit;
    int stride = gridDim.x * blockDim.x;
    for (int i = blockIdx.x * blockDim.x + threadIdx.x; i < total; i += stride) {
        if (i < wt) {
            int2 rc = w_srec[i];
            int pos = w_off[rc.x] + atomicAdd(&w_cur[rc.x], 1);
            w_pairs[pos] = make_int2(rc.y, __float_as_int(w_sval[i]));
        } else {
            int j = i - wt;
            int2 rc = wi_rc[j];
            int pos = wi_off[rc.x] + atomicAdd(&wi_cur[rc.x], 1);
            wi_pairs[pos] = make_int2(rc.y, __float_as_int(wi_cf[j]));
        }
    }
}

// ---- list-driven CSR gather, [node][B][C] layout, float4/thread, grid-stride ----
template<int C>
__global__ void gather_list(const float* __restrict__ src, float* __restrict__ dst,
                            const int* __restrict__ off, const int* __restrict__ len,
                            const int2* __restrict__ pairs, const int* __restrict__ rowlist,
                            const int* __restrict__ rowcount) {
    constexpr int C4 = C / 4;
    constexpr int TPR = C4 * B;
    constexpr int STRIDE = B * C4;        // float4 stride per source node block
    int total = (*rowcount) * TPR;
    int gstride = gridDim.x * blockDim.x;
    for (int idx = blockIdx.x * blockDim.x + threadIdx.x; idx < total; idx += gstride) {
        int row = rowlist[idx / TPR];
        int rem = idx & (TPR - 1);
        int c4 = rem & (C4 - 1);
        int b = rem / C4;
        int s = off[row];
        int L = len[row];
        const float4* sb = (const float4*)src + b * C4 + c4;
        float4 acc = make_float4(0.f, 0.f, 0.f, 0.f);
        int i = s;
        int e4i = s + (L & ~3);
        for (; i < e4i; i += 4) {
            int2 p0 = pairs[i + 0];
            int2 p1 = pairs[i + 1];
            int2 p2 = pairs[i + 2];
            int2 p3 = pairs[i + 3];
            float4 s0 = sb[(size_t)p0.x * STRIDE];
            float4 s1 = sb[(size_t)p1.x * STRIDE];
            float4 s2 = sb[(size_t)p2.x * STRIDE];
            float4 s3 = sb[(size_t)p3.x * STRIDE];
            float v0 = __int_as_float(p0.y), v1 = __int_as_float(p1.y);
            float v2 = __int_as_float(p2.y), v3 = __int_as_float(p3.y);
            acc.x += v0 * s0.x + v1 * s1.x + v2 * s2.x + v3 * s3.x;
            acc.y += v0 * s0.y + v1 * s1.y + v2 * s2.y + v3 * s3.y;
            acc.z += v0 * s0.z + v1 * s1.z + v2 * s2.z + v3 * s3.z;
            acc.w += v0 * s0.w + v1 * s1.w + v2 * s2.w + v3 * s3.w;
        }
        for (; i < s + L; ++i) {
            int2 p = pairs[i];
            float4 sv = sb[(size_t)p.x * STRIDE];
            float v = __int_as_float(p.y);
            acc.x += v * sv.x; acc.y += v * sv.y; acc.z += v * sv.z; acc.w += v * sv.w;
        }
        ((float4*)dst)[(size_t)row * STRIDE + b * C4 + c4] = acc;
    }
}

// ---------- gemm2 over n1 list: h2[n][b][:16] = lrelu(x1[n][b][:32]) @ W2 ----------
__global__ void gemm2_list(const float* __restrict__ x1, const float* __restrict__ W2,
                           float* __restrict__ h2,
                           const int* __restrict__ n1list, const int* __restrict__ n1tail) {
    __shared__ float sW[32 * 16];
    for (int i = threadIdx.x; i < 512; i += blockDim.x) sW[i] = W2[i];
    __syncthreads();
    int total = (*n1tail) * B;
    int gstride = gridDim.x * blockDim.x;
    for (int id = blockIdx.x * blockDim.x + threadIdx.x; id < total; id += gstride) {
        int n = n1list[id >> 2];
        int b = id & 3;
        const float* xr = x1 + ((size_t)n * B + b) * 32;
        float acc[16];
#pragma unroll
        for (int c = 0; c < 16; ++c) acc[c] = 0.f;
#pragma unroll
        for (int k = 0; k < 32; ++k) {
            float xv = xr[k];
            xv = xv > 0.f ? xv : NEG_SLOPE * xv;
#pragma unroll
            for (int c = 0; c < 16; ++c) acc[c] += xv * sW[k * 16 + c];
        }
        float* o = h2 + ((size_t)n * B + b) * 16;
#pragma unroll
        for (int c = 0; c < 16; ++c) o[c] = acc[c];
    }
}

// ---- t2 gather + x2 accumulation + heads, ONE block of 1024 threads ----
// t2 writes then reads are same-block (visible after __syncthreads: compiler
// emits s_waitcnt vmcnt(0) before s_barrier). No grid barrier needed.
__global__ void t2x2heads(const float* __restrict__ h2,
                          const int* __restrict__ w_off, const int* __restrict__ w_cnt,
                          const int2* __restrict__ w_pairs,
                          const int* __restrict__ r2list, const int* __restrict__ r2tail,
                          float* __restrict__ t2,
                          const int2* __restrict__ x2list, const int* __restrict__ x2tail,
                          const float* __restrict__ diag2,
                          const float* __restrict__ rw1, const float* __restrict__ rb1,
                          const float* __restrict__ rw2, const float* __restrict__ rb2,
                          float* __restrict__ out) {
    // phase 1: t2 gather over r2 rows, 16 float4-lanes per row
    int r2c = *r2tail; if (r2c > R2_CAP) r2c = R2_CAP;
    for (int idx = threadIdx.x; idx < r2c * 16; idx += blockDim.x) {
        int row = r2list[idx >> 4];
        int rem = idx & 15;
        int c4 = rem & 3;
        int b = rem >> 2;
        int s = w_off[row];
        int L = w_cnt[row];
        const float4* sb = (const float4*)h2 + b * 4 + c4;
        float4 acc = make_float4(0.f, 0.f, 0.f, 0.f);
        for (int i = s; i < s + L; ++i) {
            int2 p = w_pairs[i];
            float4 sv = sb[(size_t)p.x * 16];
            float v = __int_as_float(p.y);
            acc.x += v * sv.x; acc.y += v * sv.y; acc.z += v * sv.z; acc.w += v * sv.w;
        }
        ((float4*)t2)[(size_t)row * 16 + b * 4 + c4] = acc;
    }
    __syncthreads();

    // phase 2: x2 accumulation, edge-parallel across 16 groups of 64 lanes
    int cnt = *x2tail; if (cnt > X2_CAP) cnt = X2_CAP;
    int g = threadIdx.x >> 6, l = threadIdx.x & 63;
    int b = l >> 4, c = l & 15;
    float a0 = 0.f, a1 = 0.f;
    for (int i = g; i < cnt; i += 16) {
        int2 rec = x2list[i];
        int col = rec.x >> 1;
        float coef = __int_as_float(rec.y) * diag2[col];
        float v = t2[((size_t)col * B + b) * 16 + c] * coef;
        if (rec.x & 1) a1 += v; else a0 += v;
    }
    __shared__ float red0[16][64], red1[16][64], xs[2][64];
    red0[g][l] = a0; red1[g][l] = a1;
    __syncthreads();
    if (threadIdx.x < 64) {
        float s0 = 0.f, s1 = 0.f;
#pragma unroll
        for (int gg = 0; gg < 16; ++gg) { s0 += red0[gg][l]; s1 += red1[gg][l]; }
        xs[0][l] = s0; xs[1][l] = s1;
    }
    __syncthreads();
    if (threadIdx.x < 8) {
        int bb = threadIdx.x >> 1, which = threadIdx.x & 1;
        const float* w = which ? rw2 : rw1;
        float acc = which ? rb2[0] : rb1[0];
        for (int k = 0; k < 16; ++k) {
            float xv = xs[which][bb * 16 + k];
            xv = xv > 0.f ? xv : NEG_SLOPE * xv;
            acc += xv * w[k];
        }
        out[bb * 2 + which] = acc;
    }
}

extern "C" void kernel_launch(void* const* d_in, const int* in_sizes, int n_in,
                              void* d_out, int out_size, void* d_ws, size_t ws_size,
                              hipStream_t stream) {
    const int*   w_rows  = (const int*)d_in[0];
    const int*   w_cols  = ((const int*)d_in[0]) + E;
    const float* w_val   = (const float*)d_in[1];
    const int*   wi_rows = (const int*)d_in[2];
    const int*   wi_cols = ((const int*)d_in[2]) + E;
    const float* wi_val  = (const float*)d_in[3];
    const float* x       = (const float*)d_in[4];
    const float* W1      = (const float*)d_in[5];
    const float* diag1   = (const float*)d_in[6];
    const float* W2      = (const float*)d_in[7];
    const float* diag2   = (const float*)d_in[8];
    const float* rw1     = (const float*)d_in[9];
    const float* rb1     = (const float*)d_in[10];
    const float* rw2     = (const float*)d_in[11];
    const float* rb2     = (const float*)d_in[12];
    float* out = (float*)d_out;

    // ---------------- workspace layout ----------------
    float* h1   = (float*)d_ws;                 // [N][B][32]; later aliased as x1
    float* treg = h1 + (size_t)B * N * 32;      // 12.8M floats: staging early; t1; h2+t2 later
    int* ip = (int*)(treg + (size_t)B * R * 32);
    // zeroed block:
    int* w_cnt  = ip; ip += R;
    int* w_off  = ip; ip += R;
    int* w_cur  = ip; ip += R;
    int* wi_cnt = ip; ip += N;
    int* wi_off = ip; ip += N;
    int* wi_cur = ip; ip += N;
    int* flagsR = ip; ip += R;
    int* flagN1 = ip; ip += N;
    int* gcur   = ip; ip += 2;
    int* tails  = ip; ip += 4;   // [0]=wtail [1]=witail [2]=x2tail
    int* misc   = ip; ip += 4;   // [0]=r1tail [1]=n1tail [2]=r2tail
    size_t zero_words = (size_t)(ip - w_cnt);
    // un-zeroed:
    int2* w_pairs  = (int2*)ip; ip += 2 * E;
    int2* wi_pairs = (int2*)ip; ip += 2 * WI_CAP;
    int2* x2list   = (int2*)ip; ip += 2 * X2_CAP;
    int*  r2list   = ip; ip += R2_CAP;
    int*  n1list   = ip; ip += N;
    int*  r1list   = ip; ip += R;
    // staging buffers aliased inside treg (dead before t1 is written):
    int2*  w_srec = (int2*)treg;                                   // up to E
    float* w_sval = treg + (size_t)2 * E;                          // up to E
    int2*  wi_rc  = (int2*)(treg + (size_t)3 * E);                 // WI_CAP
    float* wi_cf  = treg + (size_t)3 * E + (size_t)2 * WI_CAP;     // WI_CAP

    float* x1 = h1;                          // alias
    float* h2 = treg;                        // [N][B][16]
    float* t2 = treg + (size_t)B * N * 16;   // [R][B][16]

    const int blk = 256;
    const int e4 = E / 4;
    const int G1 = (N * B + blk - 1) / blk;            // gemm1 blocks
    const int G2 = (e4 + blk * 4 - 1) / (blk * 4);     // markA blocks
    const int stageGrid = (e4 + I4PB - 1) / I4PB;

    (void)hipMemsetAsync(w_cnt, 0, zero_words * sizeof(int), stream);

    // ---- gemm1 + markA fused (independent work, one dispatch) ----
    fusedA<<<G1 + G2, blk, 0, stream>>>(x, W1, h1, (const int4*)wi_rows, wi_cols, wi_val,
                                        flagsR, x2list, tails + 2, r2list, misc + 2, e4, G1);
    markB<<<stageGrid, blk, 0, stream>>>((const int4*)w_rows, w_cols, flagsR, flagN1,
                                         n1list, misc + 1, e4);
    markC_wi<<<stageGrid, blk, 0, stream>>>((const int4*)wi_rows, wi_cols, wi_val, diag1,
                                            flagN1, flagsR, wi_cnt, wi_rc, wi_cf,
                                            tails + 1, r1list, misc + 0, e4);
    whist<<<stageGrid, blk, 0, stream>>>((const int4*)w_rows, w_cols, w_val, flagsR,
                                         w_cnt, w_srec, w_sval, tails + 0, e4);
    {
        int nBlocks = (R + 255) / 256 + (N + 255) / 256;
        assign_offsets2<<<nBlocks, 256, 0, stream>>>(w_cnt, R, w_off, wi_cnt, N, wi_off, gcur);
    }
    place_fused<<<512, blk, 0, stream>>>(w_srec, w_sval, tails + 0, w_off, w_cur,
                                         wi_rc, wi_cf, tails + 1, wi_off, wi_cur,
                                         w_pairs, wi_pairs);

    // ---- layer 1 gathers (list-driven, grid-stride) ----
    gather_list<32><<<4096, blk, 0, stream>>>(h1, treg, w_off, w_cnt, w_pairs,
                                              r1list, misc + 0);       // t1
    gather_list<32><<<256, blk, 0, stream>>>(treg, x1, wi_off, wi_cnt, wi_pairs,
                                             n1list, misc + 1);        // x1

    // ---- layer 2: gemm2 over n1 rows, then single-block t2+x2+heads ----
    gemm2_list<<<64, blk, 0, stream>>>(x1, W2, h2, n1list, misc + 1);
    t2x2heads<<<1, 1024, 0, stream>>>(h2, w_off, w_cnt, w_pairs, r2list, misc + 2,
                                      t2, x2list, tails + 2, diag2,
                                      rw1, rb1, rw2, rb2, out);
}

// Round 10
// 266.313 us; speedup vs baseline: 1.3020x; 1.2852x over previous
//
#include <hip/hip_runtime.h>

#define NEG_SLOPE 0.2f

static const int B = 4, N = 50000, R = 100000, E = 1600000;
static const int X2_CAP = 4096;     // x2 edge list capacity (expected ~64)
static const int R2_CAP = 4096;     // distinct t2 rows (expected ~64)
static const int N1_CAP = 4096;     // n1 slots (expected ~1k)
static const int WDEG  = 64;        // dense w-CSR slab per R-row (mean deg 16)
static const int WIDEG = 96;        // dense wi-CSR slab per n1-slot (mean deg 32)
static const int I4PB = 512;        // int4 groups per staged-scan block (2048 edges)

// flagsR bits: 1 = R2 (rows needed for t2), 2 = R1 (rows needed for t1)

// ---------- fusedA: blocks [0,G1) = gemm1 (x->h1), blocks [G1,..) = markA ----------
__global__ void fusedA(const float* __restrict__ x, const float* __restrict__ W1,
                       float* __restrict__ h1,
                       const int4* __restrict__ wi_rows4, const int* __restrict__ wi_cols,
                       const float* __restrict__ wi_val,
                       int* __restrict__ flagsR, int2* __restrict__ x2list,
                       int* __restrict__ x2tail, int* __restrict__ r2list,
                       int* __restrict__ r2tail, int e4, int G1) {
    if ((int)blockIdx.x < G1) {
        __shared__ float sW[32 * 32];
        for (int i = threadIdx.x; i < 1024; i += blockDim.x) sW[i] = W1[i];
        __syncthreads();
        int id = blockIdx.x * blockDim.x + threadIdx.x;
        if (id >= N * B) return;
        int n = id >> 2, b = id & 3;
        const float* xr = x + ((size_t)b * N + n) * 32;
        float acc[32];
#pragma unroll
        for (int c = 0; c < 32; ++c) acc[c] = 0.f;
#pragma unroll
        for (int k = 0; k < 32; ++k) {
            float xv = xr[k];
#pragma unroll
            for (int c = 0; c < 32; ++c) acc[c] += xv * sW[k * 32 + c];
        }
        float* o = h1 + ((size_t)n * B + b) * 32;
#pragma unroll
        for (int c = 0; c < 32; ++c) o[c] = acc[c];
    } else {
        int blk = blockIdx.x - G1;
        int base = blk * (blockDim.x * 4) + threadIdx.x;
#pragma unroll
        for (int k = 0; k < 4; ++k) {
            int i = base + k * blockDim.x;
            if (i >= e4) continue;
            int4 r = wi_rows4[i];
            int rr[4] = {r.x, r.y, r.z, r.w};
#pragma unroll
            for (int j = 0; j < 4; ++j) {
                if (rr[j] >= N - 2) {
                    int ed = i * 4 + j;
                    int col = wi_cols[ed];
                    int old = atomicOr(&flagsR[col], 1);
                    if (!(old & 1)) {
                        int p = atomicAdd(r2tail, 1);
                        if (p < R2_CAP) r2list[p] = col;
                    }
                    int pos = atomicAdd(x2tail, 1);   // ~64 total: negligible
                    if (pos < X2_CAP)
                        x2list[pos] = make_int2(col * 2 + (rr[j] - (N - 2)),
                                                __float_as_int(wi_val[ed]));
                }
            }
        }
    }
}

// ---- markB: w edges with flagged row -> flagN1[col], n1list append + slot map ----
__global__ void markB(const int4* __restrict__ w_rows4, const int* __restrict__ w_cols,
                      const int* __restrict__ flagsR, int* __restrict__ flagN1,
                      int* __restrict__ n1list, int* __restrict__ n1slot,
                      int* __restrict__ n1tail, int e4) {
    __shared__ int lcount, gbase;
    __shared__ int sbuf[2048];
    if (threadIdx.x == 0) lcount = 0;
    __syncthreads();
    int lane = threadIdx.x & 63;
#pragma unroll
    for (int k = 0; k < 2; ++k) {
        int i = blockIdx.x * I4PB + k * 256 + threadIdx.x;
        int4 r = make_int4(-1, -1, -1, -1);
        if (i < e4) r = w_rows4[i];
        int rr[4] = {r.x, r.y, r.z, r.w};
#pragma unroll
        for (int j = 0; j < 4; ++j) {
            bool isnew = false;
            int c = 0;
            if (rr[j] >= 0 && flagsR[rr[j]] != 0) {
                c = w_cols[i * 4 + j];
                int old = atomicOr(&flagN1[c], 1);
                isnew = (old == 0);
            }
            unsigned long long m = __ballot(isnew);
            if (m) {
                int leader = __ffsll(m) - 1;
                int b0 = 0;
                if (lane == leader) b0 = atomicAdd(&lcount, __popcll(m));
                b0 = __shfl(b0, leader);
                if (isnew) sbuf[b0 + __popcll(m & ((1ull << lane) - 1))] = c;
            }
        }
    }
    __syncthreads();
    if (threadIdx.x == 0) gbase = atomicAdd(n1tail, lcount);
    __syncthreads();
    for (int t = threadIdx.x; t < lcount; t += blockDim.x) {
        int n = sbuf[t];
        int slot = gbase + t;
        n1list[slot] = n;
        n1slot[n] = slot;
    }
}

// ---- markC_wi: wi edges with flagN1 row -> flagsR bit1 + r1list, direct wi place ---
__global__ void markC_wi(const int4* __restrict__ wi_rows4, const int* __restrict__ wi_cols,
                         const float* __restrict__ wi_val, const float* __restrict__ diag1,
                         const int* __restrict__ flagN1, const int* __restrict__ n1slot,
                         int* __restrict__ flagsR, int* __restrict__ wi_cnt,
                         int2* __restrict__ wi_pairsD,
                         int* __restrict__ r1list, int* __restrict__ r1tail, int e4) {
    __shared__ int lcount2, gbase2;
    __shared__ int r1buf[2048];
    if (threadIdx.x == 0) lcount2 = 0;
    __syncthreads();
    int lane = threadIdx.x & 63;
#pragma unroll
    for (int k = 0; k < 2; ++k) {
        int i = blockIdx.x * I4PB + k * 256 + threadIdx.x;
        int4 r = make_int4(-1, -1, -1, -1);
        if (i < e4) r = wi_rows4[i];
        int rr[4] = {r.x, r.y, r.z, r.w};
#pragma unroll
        for (int j = 0; j < 4; ++j) {
            bool isnew = false;
            if (rr[j] >= 0 && flagN1[rr[j]] != 0) {
                int ed = i * 4 + j;
                int col = wi_cols[ed];
                float cf = wi_val[ed] * diag1[col];
                int slot = n1slot[rr[j]];
                int pos = atomicAdd(&wi_cnt[rr[j]], 1);
                if (slot < N1_CAP && pos < WIDEG)
                    wi_pairsD[(size_t)slot * WIDEG + pos] =
                        make_int2(col, __float_as_int(cf));
                int old = atomicOr(&flagsR[col], 2);
                isnew = !(old & 2);
                if (isnew) { /* staged below */ }
            }
            unsigned long long m2 = __ballot(isnew);
            if (m2) {
                int leader = __ffsll(m2) - 1;
                int b0 = 0;
                if (lane == leader) b0 = atomicAdd(&lcount2, __popcll(m2));
                b0 = __shfl(b0, leader);
                if (isnew)
                    r1buf[b0 + __popcll(m2 & ((1ull << lane) - 1))] =
                        wi_cols[i * 4 + j];
            }
        }
    }
    __syncthreads();
    if (threadIdx.x == 0) gbase2 = atomicAdd(r1tail, lcount2);
    __syncthreads();
    for (int t = threadIdx.x; t < lcount2; t += blockDim.x) r1list[gbase2 + t] = r1buf[t];
}

// ---- wplace: w edges with flagsR row -> direct-dense slab write + count ----
__global__ void wplace(const int4* __restrict__ w_rows4, const int* __restrict__ w_cols,
                       const float* __restrict__ w_val, const int* __restrict__ flagsR,
                       int* __restrict__ w_cnt, int2* __restrict__ w_pairsD, int e4) {
    int base = blockIdx.x * I4PB + threadIdx.x;
#pragma unroll
    for (int k = 0; k < 2; ++k) {
        int i = base + k * 256;
        if (i >= e4) continue;
        int4 r = w_rows4[i];
        int rr[4] = {r.x, r.y, r.z, r.w};
#pragma unroll
        for (int j = 0; j < 4; ++j) {
            int row = rr[j];
            if (flagsR[row] != 0) {
                int ed = i * 4 + j;
                int pos = atomicAdd(&w_cnt[row], 1);
                if (pos < WDEG)
                    w_pairsD[(size_t)row * WDEG + pos] =
                        make_int2(w_cols[ed], __float_as_int(w_val[ed]));
            }
        }
    }
}

// ---- t1 gather: list-driven over r1 rows, dense slabs, float4/thread ----
__global__ void gather_t1(const float* __restrict__ h1, float* __restrict__ t1,
                          const int* __restrict__ w_cnt, const int2* __restrict__ w_pairsD,
                          const int* __restrict__ r1list, const int* __restrict__ r1tail) {
    // C=32: 8 float4 lanes x B=4 -> 32 threads per row
    int total = (*r1tail) * 32;
    int gstride = gridDim.x * blockDim.x;
    for (int idx = blockIdx.x * blockDim.x + threadIdx.x; idx < total; idx += gstride) {
        int row = r1list[idx >> 5];
        int rem = idx & 31;
        int c4 = rem & 7;
        int b = rem >> 3;
        int L = w_cnt[row]; if (L > WDEG) L = WDEG;
        const int2* pr = w_pairsD + (size_t)row * WDEG;
        const float4* sb = (const float4*)h1 + b * 8 + c4;
        float4 acc = make_float4(0.f, 0.f, 0.f, 0.f);
        int i = 0;
        int L4 = L & ~3;
        for (; i < L4; i += 4) {
            int2 p0 = pr[i + 0];
            int2 p1 = pr[i + 1];
            int2 p2 = pr[i + 2];
            int2 p3 = pr[i + 3];
            float4 s0 = sb[(size_t)p0.x * 32];
            float4 s1 = sb[(size_t)p1.x * 32];
            float4 s2 = sb[(size_t)p2.x * 32];
            float4 s3 = sb[(size_t)p3.x * 32];
            float v0 = __int_as_float(p0.y), v1 = __int_as_float(p1.y);
            float v2 = __int_as_float(p2.y), v3 = __int_as_float(p3.y);
            acc.x += v0 * s0.x + v1 * s1.x + v2 * s2.x + v3 * s3.x;
            acc.y += v0 * s0.y + v1 * s1.y + v2 * s2.y + v3 * s3.y;
            acc.z += v0 * s0.z + v1 * s1.z + v2 * s2.z + v3 * s3.z;
            acc.w += v0 * s0.w + v1 * s1.w + v2 * s2.w + v3 * s3.w;
        }
        for (; i < L; ++i) {
            int2 p = pr[i];
            float4 sv = sb[(size_t)p.x * 32];
            float v = __int_as_float(p.y);
            acc.x += v * sv.x; acc.y += v * sv.y; acc.z += v * sv.z; acc.w += v * sv.w;
        }
        ((float4*)t1)[(size_t)row * 32 + b * 8 + c4] = acc;
    }
}

// ---- fused x1 gather + gemm2: per n1 slot, 32 threads; x1 stays in LDS ----
// x1[n][b][:] = lrelu(sum wi-pairs) ; h2[n][b][:16] = x1row @ W2
__global__ void x1gemm2(const float* __restrict__ t1, const float* __restrict__ W2,
                        float* __restrict__ h2,
                        const int* __restrict__ n1list, const int* __restrict__ wi_cnt,
                        const int2* __restrict__ wi_pairsD,
                        const int* __restrict__ n1tail) {
    __shared__ float sW[32 * 16];
    __shared__ float xls[8][128];            // 8 rows/block x [B][32]
    for (int i = threadIdx.x; i < 512; i += blockDim.x) sW[i] = W2[i];
    int n1c = *n1tail; if (n1c > N1_CAP) n1c = N1_CAP;
    int g = threadIdx.x >> 5;                // row group 0..7
    int t32 = threadIdx.x & 31;
    int b = t32 >> 3, c4 = t32 & 7;
    for (int base = blockIdx.x * 8; base < n1c; base += gridDim.x * 8) {
        int s = base + g;
        bool active = (s < n1c);
        int n = 0;
        if (active) {
            n = n1list[s];
            int L = wi_cnt[n]; if (L > WIDEG) L = WIDEG;
            const int2* pr = wi_pairsD + (size_t)s * WIDEG;
            const float4* sb = (const float4*)t1 + b * 8 + c4;
            float4 acc = make_float4(0.f, 0.f, 0.f, 0.f);
            int i = 0;
            int L2 = L & ~1;
            for (; i < L2; i += 2) {
                int2 p0 = pr[i + 0];
                int2 p1 = pr[i + 1];
                float4 s0 = sb[(size_t)p0.x * 32];
                float4 s1 = sb[(size_t)p1.x * 32];
                float v0 = __int_as_float(p0.y), v1 = __int_as_float(p1.y);
                acc.x += v0 * s0.x + v1 * s1.x;
                acc.y += v0 * s0.y + v1 * s1.y;
                acc.z += v0 * s0.z + v1 * s1.z;
                acc.w += v0 * s0.w + v1 * s1.w;
            }
            if (i < L) {
                int2 p = pr[i];
                float4 sv = sb[(size_t)p.x * 32];
                float v = __int_as_float(p.y);
                acc.x += v * sv.x; acc.y += v * sv.y; acc.z += v * sv.z; acc.w += v * sv.w;
            }
            // lrelu applied here; gemm2 consumes lrelu'd x1
            float* xp = &xls[g][b * 32 + c4 * 4];
            xp[0] = acc.x > 0.f ? acc.x : NEG_SLOPE * acc.x;
            xp[1] = acc.y > 0.f ? acc.y : NEG_SLOPE * acc.y;
            xp[2] = acc.z > 0.f ? acc.z : NEG_SLOPE * acc.z;
            xp[3] = acc.w > 0.f ? acc.w : NEG_SLOPE * acc.w;
        }
        __syncthreads();
        if (active) {
            // two outputs per thread: o = t32 and t32+32 ; o = b*16+c
#pragma unroll
            for (int half = 0; half < 2; ++half) {
                int o = t32 + half * 32;
                int bb = o >> 4, cc = o & 15;
                const float* xp = &xls[g][bb * 32];
                float acc = 0.f;
#pragma unroll
                for (int k = 0; k < 32; ++k) acc += xp[k] * sW[k * 16 + cc];
                h2[(size_t)n * 64 + o] = acc;
            }
        }
        __syncthreads();
    }
}

// ---- t2 gather + x2 accumulation + heads, ONE block of 1024 threads ----
__global__ void t2x2heads(const float* __restrict__ h2,
                          const int* __restrict__ w_cnt, const int2* __restrict__ w_pairsD,
                          const int* __restrict__ n1slot,
                          const int* __restrict__ r2list, const int* __restrict__ r2tail,
                          float* __restrict__ t2,
                          const int2* __restrict__ x2list, const int* __restrict__ x2tail,
                          const float* __restrict__ diag2,
                          const float* __restrict__ rw1, const float* __restrict__ rb1,
                          const float* __restrict__ rw2, const float* __restrict__ rb2,
                          float* __restrict__ out) {
    // phase 1: t2 gather over r2 rows, 16 float4-lanes per row
    int r2c = *r2tail; if (r2c > R2_CAP) r2c = R2_CAP;
    for (int idx = threadIdx.x; idx < r2c * 16; idx += blockDim.x) {
        int row = r2list[idx >> 4];
        int rem = idx & 15;
        int c4 = rem & 3;
        int b = rem >> 2;
        int L = w_cnt[row]; if (L > WDEG) L = WDEG;
        const int2* pr = w_pairsD + (size_t)row * WDEG;
        const float4* sb = (const float4*)h2 + b * 4 + c4;
        float4 acc = make_float4(0.f, 0.f, 0.f, 0.f);
        for (int i = 0; i < L; ++i) {
            int2 p = pr[i];
            float4 sv = sb[(size_t)p.x * 16];
            float v = __int_as_float(p.y);
            acc.x += v * sv.x; acc.y += v * sv.y; acc.z += v * sv.z; acc.w += v * sv.w;
        }
        ((float4*)t2)[(size_t)row * 16 + b * 4 + c4] = acc;
    }
    __syncthreads();

    // phase 2: x2 accumulation, edge-parallel across 16 groups of 64 lanes
    int cnt = *x2tail; if (cnt > X2_CAP) cnt = X2_CAP;
    int g = threadIdx.x >> 6, l = threadIdx.x & 63;
    int b = l >> 4, c = l & 15;
    float a0 = 0.f, a1 = 0.f;
    for (int i = g; i < cnt; i += 16) {
        int2 rec = x2list[i];
        int col = rec.x >> 1;
        float coef = __int_as_float(rec.y) * diag2[col];
        float v = t2[(size_t)col * 64 + b * 16 + c] * coef;
        if (rec.x & 1) a1 += v; else a0 += v;
    }
    __shared__ float red0[16][64], red1[16][64], xs[2][64];
    red0[g][l] = a0; red1[g][l] = a1;
    __syncthreads();
    if (threadIdx.x < 64) {
        float s0 = 0.f, s1 = 0.f;
#pragma unroll
        for (int gg = 0; gg < 16; ++gg) { s0 += red0[gg][l]; s1 += red1[gg][l]; }
        xs[0][l] = s0; xs[1][l] = s1;
    }
    __syncthreads();
    if (threadIdx.x < 8) {
        int bb = threadIdx.x >> 1, which = threadIdx.x & 1;
        const float* w = which ? rw2 : rw1;
        float acc = which ? rb2[0] : rb1[0];
        for (int k = 0; k < 16; ++k) {
            float xv = xs[which][bb * 16 + k];
            xv = xv > 0.f ? xv : NEG_SLOPE * xv;
            acc += xv * w[k];
        }
        out[bb * 2 + which] = acc;
    }
}

extern "C" void kernel_launch(void* const* d_in, const int* in_sizes, int n_in,
                              void* d_out, int out_size, void* d_ws, size_t ws_size,
                              hipStream_t stream) {
    const int*   w_rows  = (const int*)d_in[0];
    const int*   w_cols  = ((const int*)d_in[0]) + E;
    const float* w_val   = (const float*)d_in[1];
    const int*   wi_rows = (const int*)d_in[2];
    const int*   wi_cols = ((const int*)d_in[2]) + E;
    const float* wi_val  = (const float*)d_in[3];
    const float* x       = (const float*)d_in[4];
    const float* W1      = (const float*)d_in[5];
    const float* diag1   = (const float*)d_in[6];
    const float* W2      = (const float*)d_in[7];
    const float* diag2   = (const float*)d_in[8];
    const float* rw1     = (const float*)d_in[9];
    const float* rb1     = (const float*)d_in[10];
    const float* rw2     = (const float*)d_in[11];
    const float* rb2     = (const float*)d_in[12];
    float* out = (float*)d_out;

    // ---------------- workspace layout ----------------
    float* h1 = (float*)d_ws;                    // [N][B][32] (25.6 MB)
    float* t1 = h1 + (size_t)B * N * 32;         // [R][B][32] (51.2 MB); t2 aliases later
    float* h2 = t1 + (size_t)B * R * 32;         // [N][B][16] (12.8 MB), non-aliasing
    int* ip = (int*)(h2 + (size_t)B * N * 16);
    // zeroed block:
    int* w_cnt  = ip; ip += R;
    int* wi_cnt = ip; ip += N;
    int* flagsR = ip; ip += R;
    int* flagN1 = ip; ip += N;
    int* tails  = ip; ip += 8;   // [0]=x2tail [1]=r2tail [2]=n1tail [3]=r1tail
    size_t zero_words = (size_t)(ip - w_cnt);
    // un-zeroed:
    int*  n1slot = ip; ip += N;
    int*  n1list = ip; ip += N;
    int*  r1list = ip; ip += R;
    int*  r2list = ip; ip += R2_CAP;
    int2* x2list = (int2*)ip; ip += 2 * X2_CAP;
    int2* w_pairsD  = (int2*)ip; ip += 2 * (size_t)R * WDEG;      // 51.2 MB
    int2* wi_pairsD = (int2*)ip; ip += 2 * (size_t)N1_CAP * WIDEG;

    float* t2 = t1;                              // alias: t1 dead before t2 written

    const int blk = 256;
    const int e4 = E / 4;
    const int G1 = (N * B + blk - 1) / blk;            // gemm1 blocks
    const int G2 = (e4 + blk * 4 - 1) / (blk * 4);     // markA blocks
    const int stageGrid = (e4 + I4PB - 1) / I4PB;

    (void)hipMemsetAsync(w_cnt, 0, zero_words * sizeof(int), stream);

    // 1) gemm1 + markA fused
    fusedA<<<G1 + G2, blk, 0, stream>>>(x, W1, h1, (const int4*)wi_rows, wi_cols, wi_val,
                                        flagsR, x2list, tails + 0, r2list, tails + 1,
                                        e4, G1);
    // 2) markB: flagN1 + n1list/slot
    markB<<<stageGrid, blk, 0, stream>>>((const int4*)w_rows, w_cols, flagsR, flagN1,
                                         n1list, n1slot, tails + 2, e4);
    // 3) markC: flagsR bit2 + r1list + direct wi placement (diag1 folded)
    markC_wi<<<stageGrid, blk, 0, stream>>>((const int4*)wi_rows, wi_cols, wi_val, diag1,
                                            flagN1, n1slot, flagsR, wi_cnt, wi_pairsD,
                                            r1list, tails + 3, e4);
    // 4) w placement into dense slabs
    wplace<<<stageGrid, blk, 0, stream>>>((const int4*)w_rows, w_cols, w_val, flagsR,
                                          w_cnt, w_pairsD, e4);
    // 5) t1 gather over r1 rows
    gather_t1<<<4096, blk, 0, stream>>>(h1, t1, w_cnt, w_pairsD, r1list, tails + 3);
    // 6) fused x1 gather + gemm2 over n1 slots (x1 never hits global)
    x1gemm2<<<256, blk, 0, stream>>>(t1, W2, h2, n1list, wi_cnt, wi_pairsD, tails + 2);
    // 7) t2 gather + x2 + heads, single block
    t2x2heads<<<1, 1024, 0, stream>>>(h2, w_cnt, w_pairsD, n1slot, r2list, tails + 1,
                                      t2, x2list, tails + 0, diag2,
                                      rw1, rb1, rw2, rb2, out);
}